// Round 7
// baseline (388.438 us; speedup 1.0000x reference)
//
#include <hip/hip_runtime.h>
#include <math.h>

#define NNODES 100000
#define NFEAT  256
#define HID    128
#define NCLS   40
#define KHOP   4
#define RWSAMP 10
#define KP1    5

typedef __bf16 bf16;
typedef __attribute__((ext_vector_type(8)))  __bf16 bf16x8;
typedef __attribute__((ext_vector_type(2)))  float  f32x2;
typedef __attribute__((ext_vector_type(16))) float  f32x16;

#define LDA 132   // LDS A-tile stride (elems): 264 B = 8-B aligned, 2-way-free banks

// ---------------------------------------------------------------------------
// Prep: transpose+convert weights to bf16 [n][k] layout.
// ---------------------------------------------------------------------------
__global__ __launch_bounds__(256) void prep_w(
    const float* __restrict__ W0, const float* __restrict__ W1,
    const float* __restrict__ W2,
    bf16* __restrict__ Wt0, bf16* __restrict__ Wt1, bf16* __restrict__ Wt2)
{
    int tid = blockIdx.x * 256 + threadIdx.x;
    if (tid < 128 * 256) {
        int n = tid >> 8, k = tid & 255;
        Wt0[tid] = (bf16)W0[k * 128 + n];
    } else if (tid < 128 * 256 + 128 * 128) {
        int i = tid - 128 * 256;
        int n = i >> 7, k = i & 127;
        Wt1[i] = (bf16)W1[k * 128 + n];
    } else if (tid < 128 * 256 + 128 * 128 + 64 * 128) {
        int i = tid - (128 * 256 + 128 * 128);
        int n = i >> 7, k = i & 127;
        Wt2[i] = (n < NCLS) ? (bf16)W2[k * NCLS + n] : (bf16)0.0f;
    }
}

// ---------------------------------------------------------------------------
// K0: GEMM x@W0+b0 -> fp8 table (row-major). MFMA 32x32x16 bf16.
// Block 256 = 4 waves; M-tile 128; W streamed in BK=128 chunks; A staged
// per-wave (private LDS region); fp8 out via LDS 4x4 byte-transpose.
// ---------------------------------------------------------------------------
__global__ __launch_bounds__(256) void gemm0(
    const float* __restrict__ Af, const bf16* __restrict__ Wt,
    const float* __restrict__ bias, unsigned char* __restrict__ F8, int M)
{
    constexpr int K = NFEAT, BK = 128, LDB = BK + 4;
    __shared__ bf16 Bs[128 * LDB];
    __shared__ bf16 As[4][32 * LDB];

    const int tid  = threadIdx.x;
    const int wv   = tid >> 6;
    const int lane = tid & 63;
    const int l31  = lane & 31;
    const int lhi  = lane >> 5;
    const int blockRow = blockIdx.x * 128;
    const int rowBase  = blockRow + wv * 32;

    f32x16 acc[4];
#pragma unroll
    for (int t = 0; t < 4; ++t)
#pragma unroll
        for (int r = 0; r < 16; ++r) acc[t][r] = 0.0f;

    for (int k0 = 0; k0 < K; k0 += BK) {
        if (k0) __syncthreads();
#pragma unroll 4
        for (int l = 0; l < 8; ++l) {
            int c   = tid + l * 256;
            int row = c >> 4;
            int kc  = (c & 15) * 8;
            uint4 v = *(const uint4*)(Wt + (size_t)row * K + k0 + kc);
            *(uint2*)&Bs[row * LDB + kc]     = make_uint2(v.x, v.y);
            *(uint2*)&Bs[row * LDB + kc + 4] = make_uint2(v.z, v.w);
        }
        __syncthreads();

#pragma unroll 4
        for (int l = 0; l < 16; ++l) {
            int c  = lane + l * 64;
            int r  = c >> 5;
            int kc = (c & 31) * 4;
            int gr = min(rowBase + r, M - 1);
            float4 v = *(const float4*)(Af + (size_t)gr * K + k0 + kc);
            union { bf16 h[4]; uint2 u; } t4;
            t4.h[0] = (bf16)v.x; t4.h[1] = (bf16)v.y;
            t4.h[2] = (bf16)v.z; t4.h[3] = (bf16)v.w;
            *(uint2*)&As[wv][r * LDB + kc] = t4.u;
        }

#pragma unroll
        for (int ks = 0; ks < BK / 16; ++ks) {
            const int ko = ks * 16 + lhi * 8;
            union { uint2 u2[2]; bf16x8 v; } ua, ub;
            ua.u2[0] = *(const uint2*)&As[wv][l31 * LDB + ko];
            ua.u2[1] = *(const uint2*)&As[wv][l31 * LDB + ko + 4];
            bf16x8 a = ua.v;
#pragma unroll
            for (int t = 0; t < 4; ++t) {
                ub.u2[0] = *(const uint2*)&Bs[(t * 32 + l31) * LDB + ko];
                ub.u2[1] = *(const uint2*)&Bs[(t * 32 + l31) * LDB + ko + 4];
                acc[t] = __builtin_amdgcn_mfma_f32_32x32x16_bf16(a, ub.v, acc[t], 0, 0, 0);
            }
        }
    }

    __syncthreads();
    unsigned* ldsq = (unsigned*)Bs;   // [32 rowquads][128 cols]

#pragma unroll
    for (int t = 0; t < 4; ++t) {
        int col = t * 32 + l31;
        float bc = bias[col];
#pragma unroll
        for (int G = 0; G < 4; ++G) {
            float v0 = acc[t][4 * G + 0] + bc;
            float v1 = acc[t][4 * G + 1] + bc;
            float v2 = acc[t][4 * G + 2] + bc;
            float v3 = acc[t][4 * G + 3] + bc;
            int p = __builtin_amdgcn_cvt_pk_fp8_f32(v0, v1, 0, false);
            p = __builtin_amdgcn_cvt_pk_fp8_f32(v2, v3, p, true);
            ldsq[(wv * 8 + 2 * G + lhi) * 128 + col] = (unsigned)p;
        }
    }
    __syncthreads();

    {
        const int j  = tid & 31;
        const int Q0 = (tid >> 5) * 4;
#pragma unroll
        for (int qq = 0; qq < 4; ++qq) {
            int Q = Q0 + qq;
            uint4 d = *(const uint4*)&ldsq[Q * 128 + 4 * j];
            int growb = blockRow + 4 * Q;
#pragma unroll
            for (int i = 0; i < 4; ++i) {
                unsigned sel = ((unsigned)(4 + i) << 8) | (unsigned)i;
                unsigned lo = __builtin_amdgcn_perm(d.y, d.x, sel);
                unsigned hi = __builtin_amdgcn_perm(d.w, d.z, sel);
                unsigned o  = __builtin_amdgcn_perm(hi, lo, 0x05040100u);
                if (growb + i < M)
                    *(unsigned*)(F8 + (size_t)(growb + i) * 128 + 4 * j) = o;
            }
        }
    }
}

// ---------------------------------------------------------------------------
// Shared gather-agg phase: wave wv aggregates nodes [blockRow+wv*16,+16) from
// fp8 table into LDS A-tile (bf16, relu'd). R6-proven inner loop.
// ---------------------------------------------------------------------------
__device__ __forceinline__ void agg_phase(
    bf16* As, int2 (*sew)[40],
    const unsigned char* __restrict__ f8in,
    const int* __restrict__ ends, const float* __restrict__ degree,
    const float* __restrict__ att, int blockRow, int wv, int lane)
{
    int hopoff = 0; float aw = 0.0f;
    if (lane < KHOP * RWSAMP) {
        int k = lane / RWSAMP, s = lane - k * RWSAMP;
        hopoff = k * (NNODES * RWSAMP) + s;
        aw = att[k + 1] * (1.0f / RWSAMP);
    }
    const float att0 = att[0];
    const int q  = lane >> 4;
    const int c8 = (lane & 15) * 8;

    for (int i = 0; i < 16; ++i) {
        const int n = blockRow + wv * 16 + i;
        if (n >= NNODES) continue;
        if (lane < KHOP * RWSAMP) {
            int e = ends[hopoff + n * RWSAMP];
            float w = aw * sqrtf(degree[n]) * rsqrtf(degree[e]);
            sew[wv][lane] = make_int2(e << 7, __float_as_int(w));
        }
        // wave-private LDS: same-wave producer/consumer, in-order DS pipe

        f32x2 a0 = {0.f, 0.f}, a1 = {0.f, 0.f}, a2 = {0.f, 0.f}, a3 = {0.f, 0.f};
#pragma unroll
        for (int t = 0; t < 10; ++t) {
            int2  ew   = sew[wv][4 * t + q];
            unsigned v = (unsigned)ew.x + (unsigned)c8;
            float wj   = __int_as_float(ew.y);
            f32x2 w2   = {wj, wj};
            uint2 g = *(const uint2*)(f8in + v);
            a0 = __builtin_elementwise_fma(w2, __builtin_amdgcn_cvt_pk_f32_fp8((int)g.x, false), a0);
            a1 = __builtin_elementwise_fma(w2, __builtin_amdgcn_cvt_pk_f32_fp8((int)g.x, true),  a1);
            a2 = __builtin_elementwise_fma(w2, __builtin_amdgcn_cvt_pk_f32_fp8((int)g.y, false), a2);
            a3 = __builtin_elementwise_fma(w2, __builtin_amdgcn_cvt_pk_f32_fp8((int)g.y, true),  a3);
        }

        a0.x += __shfl_xor(a0.x, 16, 64); a0.y += __shfl_xor(a0.y, 16, 64);
        a1.x += __shfl_xor(a1.x, 16, 64); a1.y += __shfl_xor(a1.y, 16, 64);
        a2.x += __shfl_xor(a2.x, 16, 64); a2.y += __shfl_xor(a2.y, 16, 64);
        a3.x += __shfl_xor(a3.x, 16, 64); a3.y += __shfl_xor(a3.y, 16, 64);
        a0.x += __shfl_xor(a0.x, 32, 64); a0.y += __shfl_xor(a0.y, 32, 64);
        a1.x += __shfl_xor(a1.x, 32, 64); a1.y += __shfl_xor(a1.y, 32, 64);
        a2.x += __shfl_xor(a2.x, 32, 64); a2.y += __shfl_xor(a2.y, 32, 64);
        a3.x += __shfl_xor(a3.x, 32, 64); a3.y += __shfl_xor(a3.y, 32, 64);

        if (q == 0) {
            f32x2 av = {att0, att0};
            unsigned vs = ((unsigned)n << 7) + (unsigned)c8;
            uint2 sv = *(const uint2*)(f8in + vs);
            a0 = __builtin_elementwise_fma(av, __builtin_amdgcn_cvt_pk_f32_fp8((int)sv.x, false), a0);
            a1 = __builtin_elementwise_fma(av, __builtin_amdgcn_cvt_pk_f32_fp8((int)sv.x, true),  a1);
            a2 = __builtin_elementwise_fma(av, __builtin_amdgcn_cvt_pk_f32_fp8((int)sv.y, false), a2);
            a3 = __builtin_elementwise_fma(av, __builtin_amdgcn_cvt_pk_f32_fp8((int)sv.y, true),  a3);

            f32x2 z = {0.f, 0.f};
            a0 = __builtin_elementwise_max(a0, z);
            a1 = __builtin_elementwise_max(a1, z);
            a2 = __builtin_elementwise_max(a2, z);
            a3 = __builtin_elementwise_max(a3, z);

            union { bf16 h[8]; uint2 u[2]; } st;
            st.h[0] = (bf16)a0.x; st.h[1] = (bf16)a0.y;
            st.h[2] = (bf16)a1.x; st.h[3] = (bf16)a1.y;
            st.h[4] = (bf16)a2.x; st.h[5] = (bf16)a2.y;
            st.h[6] = (bf16)a3.x; st.h[7] = (bf16)a3.y;
            int r = wv * 16 + i;
            *(uint2*)&As[r * LDA + c8]     = st.u[0];
            *(uint2*)&As[r * LDA + c8 + 4] = st.u[1];
        }
    }
}

// ---------------------------------------------------------------------------
// K1: fused agg(relu) -> LDS A (64x128 bf16) -> MFMA @Wt1 + b1 -> fp8 table out.
// GEMM split: wave w -> row-stripe (w&1)*32, col tiles {2*(w>>1), +1}.
// B-frags direct from global (Wt1 = 32 KB, L1-resident).
// ---------------------------------------------------------------------------
__global__ __launch_bounds__(256) void layer_fused(
    const unsigned char* __restrict__ f8in, const bf16* __restrict__ Wt,
    const float* __restrict__ bias, unsigned char* __restrict__ F8out,
    const int* __restrict__ ends, const float* __restrict__ degree,
    const float* __restrict__ att)
{
    __shared__ bf16 As[64 * LDA];
    __shared__ int2 sew[4][40];

    const int tid  = threadIdx.x;
    const int wv   = tid >> 6;
    const int lane = tid & 63;
    const int blockRow = blockIdx.x * 64;

    agg_phase(As, sew, f8in, ends, degree, att, blockRow, wv, lane);
    __syncthreads();

    const int l31 = lane & 31;
    const int lhi = lane >> 5;
    const int sp  = wv & 1;
    const int t0  = (wv >> 1) * 2;

    f32x16 acc[2];
#pragma unroll
    for (int t = 0; t < 2; ++t)
#pragma unroll
        for (int r = 0; r < 16; ++r) acc[t][r] = 0.0f;

#pragma unroll
    for (int ks = 0; ks < 8; ++ks) {
        const int ko = ks * 16 + lhi * 8;
        union { uint2 u2[2]; bf16x8 v; } ua;
        ua.u2[0] = *(const uint2*)&As[(sp * 32 + l31) * LDA + ko];
        ua.u2[1] = *(const uint2*)&As[(sp * 32 + l31) * LDA + ko + 4];
#pragma unroll
        for (int tt = 0; tt < 2; ++tt) {
            bf16x8 b = *(const bf16x8*)(Wt + (size_t)((t0 + tt) * 32 + l31) * HID + ko);
            acc[tt] = __builtin_amdgcn_mfma_f32_32x32x16_bf16(ua.v, b, acc[tt], 0, 0, 0);
        }
    }
    __syncthreads();                 // done reading As

    unsigned* ldsq = (unsigned*)As;  // [16 rowquads][128 cols]
#pragma unroll
    for (int tt = 0; tt < 2; ++tt) {
        int col = (t0 + tt) * 32 + l31;
        float bc = bias[col];
#pragma unroll
        for (int G = 0; G < 4; ++G) {
            float v0 = acc[tt][4 * G + 0] + bc;
            float v1 = acc[tt][4 * G + 1] + bc;
            float v2 = acc[tt][4 * G + 2] + bc;
            float v3 = acc[tt][4 * G + 3] + bc;
            int p = __builtin_amdgcn_cvt_pk_fp8_f32(v0, v1, 0, false);
            p = __builtin_amdgcn_cvt_pk_fp8_f32(v2, v3, p, true);
            ldsq[(sp * 8 + 2 * G + lhi) * 128 + col] = (unsigned)p;
        }
    }
    __syncthreads();

    {
        const int j = tid & 31;
#pragma unroll
        for (int qq = 0; qq < 2; ++qq) {
            int Q = (tid >> 5) * 2 + qq;
            uint4 d = *(const uint4*)&ldsq[Q * 128 + 4 * j];
            int growb = blockRow + 4 * Q;
#pragma unroll
            for (int i = 0; i < 4; ++i) {
                unsigned sel = ((unsigned)(4 + i) << 8) | (unsigned)i;
                unsigned lo = __builtin_amdgcn_perm(d.y, d.x, sel);
                unsigned hi = __builtin_amdgcn_perm(d.w, d.z, sel);
                unsigned o  = __builtin_amdgcn_perm(hi, lo, 0x05040100u);
                if (growb + i < NNODES)
                    *(unsigned*)(F8out + (size_t)(growb + i) * 128 + 4 * j) = o;
            }
        }
    }
}

// ---------------------------------------------------------------------------
// K2: fused agg(relu) -> LDS A -> MFMA @Wt2 (N=64, cols>=40 zero) + b2 ->
// fused log_softmax -> out. Waves 0,1 do the head (stripe = wv, both tiles).
// ---------------------------------------------------------------------------
__global__ __launch_bounds__(256) void head_fused(
    const unsigned char* __restrict__ f8in, const bf16* __restrict__ Wt2,
    const float* __restrict__ b2, float* __restrict__ out,
    const int* __restrict__ ends, const float* __restrict__ degree,
    const float* __restrict__ att)
{
    __shared__ bf16 As[64 * LDA];
    __shared__ int2 sew[4][40];

    const int tid  = threadIdx.x;
    const int wv   = tid >> 6;
    const int lane = tid & 63;
    const int blockRow = blockIdx.x * 64;

    agg_phase(As, sew, f8in, ends, degree, att, blockRow, wv, lane);
    __syncthreads();

    if (wv >= 2) return;

    const int l31 = lane & 31;
    const int lhi = lane >> 5;
    const int sp  = wv;

    f32x16 acc[2];
#pragma unroll
    for (int t = 0; t < 2; ++t)
#pragma unroll
        for (int r = 0; r < 16; ++r) acc[t][r] = 0.0f;

#pragma unroll
    for (int ks = 0; ks < 8; ++ks) {
        const int ko = ks * 16 + lhi * 8;
        union { uint2 u2[2]; bf16x8 v; } ua;
        ua.u2[0] = *(const uint2*)&As[(sp * 32 + l31) * LDA + ko];
        ua.u2[1] = *(const uint2*)&As[(sp * 32 + l31) * LDA + ko + 4];
#pragma unroll
        for (int tt = 0; tt < 2; ++tt) {
            bf16x8 b = *(const bf16x8*)(Wt2 + (size_t)(tt * 32 + l31) * HID + ko);
            acc[tt] = __builtin_amdgcn_mfma_f32_32x32x16_bf16(ua.v, b, acc[tt], 0, 0, 0);
        }
    }

    const float bc0 = b2[l31];
    const float bc1 = (l31 < 8) ? b2[32 + l31] : 0.0f;

#pragma unroll
    for (int r = 0; r < 16; ++r) {
        float v0 = acc[0][r] + bc0;
        float v1 = (l31 < 8) ? (acc[1][r] + bc1) : -INFINITY;

        float m = fmaxf(v0, v1);
#pragma unroll
        for (int off = 16; off > 0; off >>= 1)
            m = fmaxf(m, __shfl_xor(m, off, 64));

        float s = __expf(v0 - m) + ((l31 < 8) ? __expf(v1 - m) : 0.0f);
#pragma unroll
        for (int off = 16; off > 0; off >>= 1)
            s += __shfl_xor(s, off, 64);

        float ls = __logf(s);
        int grow = blockRow + sp * 32 + (r & 3) + 8 * (r >> 2) + 4 * lhi;
        if (grow < NNODES) {
            out[(size_t)grow * NCLS + l31] = v0 - m - ls;
            if (l31 < 8)
                out[(size_t)grow * NCLS + 32 + l31] = v1 - m - ls;
        }
    }
}

extern "C" void kernel_launch(void* const* d_in, const int* in_sizes, int n_in,
                              void* d_out, int out_size, void* d_ws, size_t ws_size,
                              hipStream_t stream)
{
    const float* x      = (const float*)d_in[0];
    const float* degree = (const float*)d_in[1];
    const int*   ends   = (const int*)  d_in[2];
    const float* att    = (const float*)d_in[3];
    const float* W0     = (const float*)d_in[4];
    const float* b0     = (const float*)d_in[5];
    const float* W1     = (const float*)d_in[6];
    const float* b1     = (const float*)d_in[7];
    const float* W2     = (const float*)d_in[8];
    const float* b2     = (const float*)d_in[9];
    float* out = (float*)d_out;

    unsigned char* f8a = (unsigned char*)d_ws;             // [NNODES,128] fp8
    unsigned char* f8b = f8a + (size_t)NNODES * HID;       // [NNODES,128] fp8
    bf16* Wt0 = (bf16*)(f8b + (size_t)NNODES * HID);       // [128,256]
    bf16* Wt1 = Wt0 + 128 * 256;                           // [128,128]
    bf16* Wt2 = Wt1 + 128 * 128;                           // [64,128]

    const int prepN = 128 * 256 + 128 * 128 + 64 * 128;
    prep_w<<<(prepN + 255) / 256, 256, 0, stream>>>(W0, W1, W2, Wt0, Wt1, Wt2);

    const int gG0 = (NNODES + 127) / 128;
    const int gF  = (NNODES + 63) / 64;

    gemm0<<<gG0, 256, 0, stream>>>(x, Wt0, b0, f8a, NNODES);
    layer_fused<<<gF, 256, 0, stream>>>(f8a, Wt1, b1, f8b, ends, degree, att);
    head_fused<<<gF, 256, 0, stream>>>(
        f8b, Wt2, b2, out, ends + (size_t)KHOP * NNODES * RWSAMP, degree, att + KP1);
}

// Round 8
// 350.686 us; speedup vs baseline: 1.1077x; 1.1077x over previous
//
#include <hip/hip_runtime.h>
#include <math.h>

#define NNODES 100000
#define NFEAT  256
#define HID    128
#define NCLS   40
#define KHOP   4
#define RWSAMP 10
#define KP1    5

typedef __bf16 bf16;
typedef __attribute__((ext_vector_type(8)))  __bf16 bf16x8;
typedef __attribute__((ext_vector_type(2)))  float  f32x2;
typedef __attribute__((ext_vector_type(16))) float  f32x16;

// ---------------------------------------------------------------------------
// Prep: transpose+convert weights to bf16 [n][k] layout.
// ---------------------------------------------------------------------------
__global__ __launch_bounds__(256) void prep_w(
    const float* __restrict__ W0, const float* __restrict__ W1,
    const float* __restrict__ W2,
    bf16* __restrict__ Wt0, bf16* __restrict__ Wt1, bf16* __restrict__ Wt2)
{
    int tid = blockIdx.x * 256 + threadIdx.x;
    if (tid < 128 * 256) {
        int n = tid >> 8, k = tid & 255;
        Wt0[tid] = (bf16)W0[k * 128 + n];
    } else if (tid < 128 * 256 + 128 * 128) {
        int i = tid - 128 * 256;
        int n = i >> 7, k = i & 127;
        Wt1[i] = (bf16)W1[k * 128 + n];
    } else if (tid < 128 * 256 + 128 * 128 + 64 * 128) {
        int i = tid - (128 * 256 + 128 * 128);
        int n = i >> 7, k = i & 127;
        Wt2[i] = (n < NCLS) ? (bf16)W2[k * NCLS + n] : (bf16)0.0f;
    }
}

// ---------------------------------------------------------------------------
// GEMM: MFMA 32x32x16 bf16; output ONLY a row-major fp8-e4m3 table
// (via LDS 4x4 byte-transpose -> coalesced dword stores). R6-proven.
// ---------------------------------------------------------------------------
template<int K, bool A_BF16>
__global__ __launch_bounds__(256) void gemm_nodes(
    const void* __restrict__ Av, const bf16* __restrict__ Wt,
    const float* __restrict__ bias, unsigned char* __restrict__ F8, int M)
{
    constexpr int BK  = 128;
    constexpr int LDB = BK + 4;
    __shared__ bf16 Bs[128 * LDB];
    __shared__ bf16 As[4][32 * LDB];

    const int tid  = threadIdx.x;
    const int wv   = tid >> 6;
    const int lane = tid & 63;
    const int l31  = lane & 31;
    const int lhi  = lane >> 5;
    const int blockRow = blockIdx.x * 128;
    const int rowBase  = blockRow + wv * 32;

    const bf16*  Ab = (const bf16*)Av;
    const float* Af = (const float*)Av;

    f32x16 acc[4];
#pragma unroll
    for (int t = 0; t < 4; ++t)
#pragma unroll
        for (int r = 0; r < 16; ++r) acc[t][r] = 0.0f;

    for (int k0 = 0; k0 < K; k0 += BK) {
        if (k0) __syncthreads();
#pragma unroll 4
        for (int l = 0; l < 8; ++l) {
            int c   = tid + l * 256;
            int row = c >> 4;
            int kc  = (c & 15) * 8;
            uint4 v = *(const uint4*)(Wt + (size_t)row * K + k0 + kc);
            *(uint2*)&Bs[row * LDB + kc]     = make_uint2(v.x, v.y);
            *(uint2*)&Bs[row * LDB + kc + 4] = make_uint2(v.z, v.w);
        }
        __syncthreads();

        if (A_BF16) {
#pragma unroll 4
            for (int l = 0; l < 8; ++l) {
                int c  = lane + l * 64;
                int r  = c >> 4;
                int kc = (c & 15) * 8;
                int gr = min(rowBase + r, M - 1);
                uint4 v = *(const uint4*)(Ab + (size_t)gr * K + k0 + kc);
                *(uint2*)&As[wv][r * LDB + kc]     = make_uint2(v.x, v.y);
                *(uint2*)&As[wv][r * LDB + kc + 4] = make_uint2(v.z, v.w);
            }
        } else {
#pragma unroll 4
            for (int l = 0; l < 16; ++l) {
                int c  = lane + l * 64;
                int r  = c >> 5;
                int kc = (c & 31) * 4;
                int gr = min(rowBase + r, M - 1);
                float4 v = *(const float4*)(Af + (size_t)gr * K + k0 + kc);
                union { bf16 h[4]; uint2 u; } t4;
                t4.h[0] = (bf16)v.x; t4.h[1] = (bf16)v.y;
                t4.h[2] = (bf16)v.z; t4.h[3] = (bf16)v.w;
                *(uint2*)&As[wv][r * LDB + kc] = t4.u;
            }
        }

#pragma unroll
        for (int ks = 0; ks < BK / 16; ++ks) {
            const int ko = ks * 16 + lhi * 8;
            union { uint2 u2[2]; bf16x8 v; } ua, ub;
            ua.u2[0] = *(const uint2*)&As[wv][l31 * LDB + ko];
            ua.u2[1] = *(const uint2*)&As[wv][l31 * LDB + ko + 4];
            bf16x8 a = ua.v;
#pragma unroll
            for (int t = 0; t < 4; ++t) {
                ub.u2[0] = *(const uint2*)&Bs[(t * 32 + l31) * LDB + ko];
                ub.u2[1] = *(const uint2*)&Bs[(t * 32 + l31) * LDB + ko + 4];
                acc[t] = __builtin_amdgcn_mfma_f32_32x32x16_bf16(a, ub.v, acc[t], 0, 0, 0);
            }
        }
    }

    __syncthreads();
    unsigned* ldsq = (unsigned*)Bs;   // [32 rowquads][128 cols]

#pragma unroll
    for (int t = 0; t < 4; ++t) {
        int col = t * 32 + l31;
        float bc = bias[col];
#pragma unroll
        for (int G = 0; G < 4; ++G) {
            float v0 = acc[t][4 * G + 0] + bc;
            float v1 = acc[t][4 * G + 1] + bc;
            float v2 = acc[t][4 * G + 2] + bc;
            float v3 = acc[t][4 * G + 3] + bc;
            int p = __builtin_amdgcn_cvt_pk_fp8_f32(v0, v1, 0, false);
            p = __builtin_amdgcn_cvt_pk_fp8_f32(v2, v3, p, true);
            ldsq[(wv * 8 + 2 * G + lhi) * 128 + col] = (unsigned)p;
        }
    }
    __syncthreads();

    {
        const int j  = tid & 31;
        const int Q0 = (tid >> 5) * 4;
#pragma unroll
        for (int qq = 0; qq < 4; ++qq) {
            int Q = Q0 + qq;
            uint4 d = *(const uint4*)&ldsq[Q * 128 + 4 * j];
            int growb = blockRow + 4 * Q;
#pragma unroll
            for (int i = 0; i < 4; ++i) {
                unsigned sel = ((unsigned)(4 + i) << 8) | (unsigned)i;
                unsigned lo = __builtin_amdgcn_perm(d.y, d.x, sel);
                unsigned hi = __builtin_amdgcn_perm(d.w, d.z, sel);
                unsigned o  = __builtin_amdgcn_perm(hi, lo, 0x05040100u);
                if (growb + i < M)
                    *(unsigned*)(F8 + (size_t)(growb + i) * 128 + 4 * j) = o;
            }
        }
    }
}

// ---------------------------------------------------------------------------
// Aggregation + ReLU, all-fp8 reads, packed-f32 math. ONE WAVE = TWO NODES
// (interleaved accumulators -> 20 outstanding gathers per lane for latency
// hiding). Lane-quarter q handles walks j=4t+q; lane owns 8 feats.
// Epilogue: quarter 0 finalizes node0, quarter 1 finalizes node1.
// ---------------------------------------------------------------------------
__global__ __launch_bounds__(256) void agg_relu_fp8(
    const unsigned char* __restrict__ hf8, bf16* __restrict__ hout,
    const int* __restrict__ ends, const float* __restrict__ degree,
    const float* __restrict__ att)
{
    __shared__ int2 sew[4][2][40];   // [wave][node][walk] = (e<<7, w bits)

    const int wv   = threadIdx.x >> 6;
    const int lane = threadIdx.x & 63;
    const int n0   = blockIdx.x * 8 + wv * 2;   // wave handles n0, n0+1

    for (int en = lane; en < 80; en += 64) {
        int which = en >= 40;
        int l = en - which * 40;
        int n = n0 + which;
        int k = l / RWSAMP, s = l - k * RWSAMP;
        int e = ends[(size_t)k * (NNODES * RWSAMP) + (size_t)n * RWSAMP + s];
        float w = att[k + 1] * (1.0f / RWSAMP) * sqrtf(degree[n]) * rsqrtf(degree[e]);
        sew[wv][which][l] = make_int2(e << 7, __float_as_int(w));
    }
    // wave-private LDS region: same-wave producer/consumer, in-order DS pipe

    const int q  = lane >> 4;
    const int c8 = (lane & 15) * 8;

    f32x2 a0[4], a1[4];
#pragma unroll
    for (int i = 0; i < 4; ++i) { a0[i] = (f32x2){0.f, 0.f}; a1[i] = (f32x2){0.f, 0.f}; }

#pragma unroll
    for (int t = 0; t < 10; ++t) {
        int2 ew0 = sew[wv][0][4 * t + q];
        int2 ew1 = sew[wv][1][4 * t + q];
        uint2 g0 = *(const uint2*)(hf8 + (unsigned)ew0.x + (unsigned)c8);
        uint2 g1 = *(const uint2*)(hf8 + (unsigned)ew1.x + (unsigned)c8);
        float w0 = __int_as_float(ew0.y);
        float w1 = __int_as_float(ew1.y);
        f32x2 w20 = {w0, w0}, w21 = {w1, w1};
        a0[0] = __builtin_elementwise_fma(w20, __builtin_amdgcn_cvt_pk_f32_fp8((int)g0.x, false), a0[0]);
        a0[1] = __builtin_elementwise_fma(w20, __builtin_amdgcn_cvt_pk_f32_fp8((int)g0.x, true),  a0[1]);
        a0[2] = __builtin_elementwise_fma(w20, __builtin_amdgcn_cvt_pk_f32_fp8((int)g0.y, false), a0[2]);
        a0[3] = __builtin_elementwise_fma(w20, __builtin_amdgcn_cvt_pk_f32_fp8((int)g0.y, true),  a0[3]);
        a1[0] = __builtin_elementwise_fma(w21, __builtin_amdgcn_cvt_pk_f32_fp8((int)g1.x, false), a1[0]);
        a1[1] = __builtin_elementwise_fma(w21, __builtin_amdgcn_cvt_pk_f32_fp8((int)g1.x, true),  a1[1]);
        a1[2] = __builtin_elementwise_fma(w21, __builtin_amdgcn_cvt_pk_f32_fp8((int)g1.y, false), a1[2]);
        a1[3] = __builtin_elementwise_fma(w21, __builtin_amdgcn_cvt_pk_f32_fp8((int)g1.y, true),  a1[3]);
    }

    // combine quarters (xor 16, 32) for both nodes
#pragma unroll
    for (int i = 0; i < 4; ++i) {
        a0[i].x += __shfl_xor(a0[i].x, 16, 64); a0[i].y += __shfl_xor(a0[i].y, 16, 64);
        a1[i].x += __shfl_xor(a1[i].x, 16, 64); a1[i].y += __shfl_xor(a1[i].y, 16, 64);
        a0[i].x += __shfl_xor(a0[i].x, 32, 64); a0[i].y += __shfl_xor(a0[i].y, 32, 64);
        a1[i].x += __shfl_xor(a1[i].x, 32, 64); a1[i].y += __shfl_xor(a1[i].y, 32, 64);
    }

    if (q < 2) {
        // quarter 0 -> node0, quarter 1 -> node1
        const int n = n0 + q;
        f32x2* a = (q == 0) ? a0 : a1;
        const float att0 = att[0];
        f32x2 av = {att0, att0};
        unsigned vs = ((unsigned)n << 7) + (unsigned)c8;
        uint2 sv = *(const uint2*)(hf8 + vs);
        a[0] = __builtin_elementwise_fma(av, __builtin_amdgcn_cvt_pk_f32_fp8((int)sv.x, false), a[0]);
        a[1] = __builtin_elementwise_fma(av, __builtin_amdgcn_cvt_pk_f32_fp8((int)sv.x, true),  a[1]);
        a[2] = __builtin_elementwise_fma(av, __builtin_amdgcn_cvt_pk_f32_fp8((int)sv.y, false), a[2]);
        a[3] = __builtin_elementwise_fma(av, __builtin_amdgcn_cvt_pk_f32_fp8((int)sv.y, true),  a[3]);

        f32x2 z = {0.f, 0.f};
#pragma unroll
        for (int i = 0; i < 4; ++i) a[i] = __builtin_elementwise_max(a[i], z);

        union { bf16 h[8]; uint4 u; } st;
        st.h[0] = (bf16)a[0].x; st.h[1] = (bf16)a[0].y;
        st.h[2] = (bf16)a[1].x; st.h[3] = (bf16)a[1].y;
        st.h[4] = (bf16)a[2].x; st.h[5] = (bf16)a[2].y;
        st.h[6] = (bf16)a[3].x; st.h[7] = (bf16)a[3].y;
        *(uint4*)(hout + (size_t)n * HID + c8) = st.u;
    }
}

// ---------------------------------------------------------------------------
// Head: logits = h @ W2 + b2 via MFMA (N=64, cols>=40 zero), fused log_softmax.
// ---------------------------------------------------------------------------
__global__ __launch_bounds__(256) void head_mfma(
    const bf16* __restrict__ h, const bf16* __restrict__ Wt2,
    const float* __restrict__ b2, float* __restrict__ out, int M)
{
    constexpr int K = HID, LDB = K + 8;
    __shared__ bf16 Bs[64 * LDB];

    const int tid = threadIdx.x;
    constexpr int CPR = K / 8;
    for (int f = tid; f < 64 * CPR; f += 256) {
        int row = f / CPR;
        int kc  = (f % CPR) * 8;
        *(uint4*)&Bs[row * LDB + kc] = *(const uint4*)(Wt2 + (size_t)row * K + kc);
    }
    __syncthreads();

    const int wv   = tid >> 6;
    const int lane = tid & 63;
    const int l31  = lane & 31;
    const int lhi  = lane >> 5;
    const int blockRow = blockIdx.x * 128;
    const int arow = min(blockRow + wv * 32 + l31, M - 1);

    f32x16 acc[2];
#pragma unroll
    for (int t = 0; t < 2; ++t)
#pragma unroll
        for (int r = 0; r < 16; ++r) acc[t][r] = 0.0f;

#pragma unroll
    for (int ks = 0; ks < K / 16; ++ks) {
        bf16x8 a = *(const bf16x8*)(h + (size_t)arow * K + ks * 16 + lhi * 8);
#pragma unroll
        for (int t = 0; t < 2; ++t) {
            bf16x8 b = *(const bf16x8*)&Bs[(t * 32 + l31) * LDB + ks * 16 + lhi * 8];
            acc[t] = __builtin_amdgcn_mfma_f32_32x32x16_bf16(a, b, acc[t], 0, 0, 0);
        }
    }

    const float bc0 = b2[l31];
    const float bc1 = (l31 < 8) ? b2[32 + l31] : 0.0f;

#pragma unroll
    for (int r = 0; r < 16; ++r) {
        float v0 = acc[0][r] + bc0;
        float v1 = (l31 < 8) ? (acc[1][r] + bc1) : -INFINITY;

        float m = fmaxf(v0, v1);
#pragma unroll
        for (int off = 16; off > 0; off >>= 1)
            m = fmaxf(m, __shfl_xor(m, off, 64));

        float s = __expf(v0 - m) + ((l31 < 8) ? __expf(v1 - m) : 0.0f);
#pragma unroll
        for (int off = 16; off > 0; off >>= 1)
            s += __shfl_xor(s, off, 64);

        float ls = __logf(s);
        int grow = blockRow + wv * 32 + (r & 3) + 8 * (r >> 2) + 4 * lhi;
        if (grow < M) {
            out[(size_t)grow * NCLS + l31] = v0 - m - ls;
            if (l31 < 8)
                out[(size_t)grow * NCLS + 32 + l31] = v1 - m - ls;
        }
    }
}

extern "C" void kernel_launch(void* const* d_in, const int* in_sizes, int n_in,
                              void* d_out, int out_size, void* d_ws, size_t ws_size,
                              hipStream_t stream)
{
    const float* x      = (const float*)d_in[0];
    const float* degree = (const float*)d_in[1];
    const int*   ends   = (const int*)  d_in[2];
    const float* att    = (const float*)d_in[3];
    const float* W0     = (const float*)d_in[4];
    const float* b0     = (const float*)d_in[5];
    const float* W1     = (const float*)d_in[6];
    const float* b1     = (const float*)d_in[7];
    const float* W2     = (const float*)d_in[8];
    const float* b2     = (const float*)d_in[9];
    float* out = (float*)d_out;

    bf16* hb0 = (bf16*)d_ws;                               // [NNODES, HID] bf16
    bf16* hb1 = hb0 + (size_t)NNODES * HID;                // [NNODES, HID] bf16
    unsigned char* hf8 = (unsigned char*)(hb1 + (size_t)NNODES * HID);  // [NNODES,128] fp8
    bf16* Wt0 = (bf16*)(hf8 + (size_t)NNODES * HID);       // [128, 256]
    bf16* Wt1 = Wt0 + 128 * 256;                           // [128, 128]
    bf16* Wt2 = Wt1 + 128 * 128;                           // [64, 128]

    const int prepN = 128 * 256 + 128 * 128 + 64 * 128;
    prep_w<<<(prepN + 255) / 256, 256, 0, stream>>>(W0, W1, W2, Wt0, Wt1, Wt2);

    const int gGemm = (NNODES + 127) / 128;
    const int gAgg  = (NNODES + 7) / 8;

    // layer 0
    gemm_nodes<NFEAT, false><<<gGemm, 256, 0, stream>>>(x, Wt0, b0, hf8, NNODES);
    agg_relu_fp8<<<gAgg, 256, 0, stream>>>(hf8, hb1, ends, degree, att);
    // layer 1
    gemm_nodes<HID, true><<<gGemm, 256, 0, stream>>>(hb1, Wt1, b1, hf8, NNODES);
    agg_relu_fp8<<<gAgg, 256, 0, stream>>>(
        hf8, hb0, ends + (size_t)KHOP * NNODES * RWSAMP, degree, att + KP1);
    // head
    head_mfma<<<gGemm, 256, 0, stream>>>(hb0, Wt2, b2, out, NNODES);
}